// Round 7
// baseline (817.670 us; speedup 1.0000x reference)
//
#include <hip/hip_runtime.h>
#include <stdint.h>

#define THRESH 0.5f
#define PSI 0.1f

typedef short bfrag_t __attribute__((ext_vector_type(8)));     // 8 bf16 = 4 VGPRs (MFMA A/B frag)
typedef float f32x16 __attribute__((ext_vector_type(16)));     // 32x32 MFMA C/D frag
typedef unsigned short u16x8 __attribute__((ext_vector_type(8)));

// async global->LDS, 16B per lane, wave-uniform LDS base + lane*16
#define GLD16(gsrc, ldst)                                                                \
    __builtin_amdgcn_global_load_lds((const __attribute__((address_space(1))) void*)(gsrc), \
                                     (__attribute__((address_space(3))) void*)(ldst),       \
                                     16, 0, 0)

#define WAITVM(n) asm volatile("s_waitcnt vmcnt(" #n ")" ::: "memory")
#define WAITLGKM0() asm volatile("s_waitcnt lgkmcnt(0)" ::: "memory")
#define BAR()                                  \
    do {                                       \
        asm volatile("" ::: "memory");         \
        __builtin_amdgcn_s_barrier();          \
        asm volatile("" ::: "memory");         \
    } while (0)

__device__ __forceinline__ float dequant(float v) {
    if (v > THRESH) return 1.0f;
    if (v < -THRESH) return -1.0f;
    if (fabsf(v) < PSI) return 0.0f;
    return (v + THRESH) / (2.0f * THRESH);
}

__device__ __forceinline__ unsigned short f2bf(float f) {
    unsigned int u = __float_as_uint(f);
    u += 0x7FFFu + ((u >> 16) & 1u);
    return (unsigned short)(u >> 16);
}

// ---------------------------------------------------------------------------
// Packing kernels: fp32 row-major [R][K] -> bf16 chunk-linear:
//   granule (r, S, hi) = 8 elems src[r][16S+8hi .. +7]
//   packed elem offset = ((r/32)*(K/16) + S)*512 + (hi*32 + (r&31))*8
// ---------------------------------------------------------------------------
template <bool DO_DEQUANT>
__global__ void pack_kernel(const float* __restrict__ src, unsigned short* __restrict__ dst, int K) {
    __shared__ char lsm[16384];
    const int t   = threadIdx.x;       // 0..255
    const int nkc = K >> 8;            // K/256
    const int b   = blockIdx.x / nkc;  // 32-row band
    const int kc  = blockIdx.x % nkc;
    const int k0  = kc << 8;
    const int r   = t >> 3;            // 0..31 row within band
    const int j   = t & 7;             // 0..7  32-float group

    const float4* s4 = (const float4*)(src + (size_t)((b << 5) + r) * K + k0 + (j << 5));
    float4 f[8];
#pragma unroll
    for (int i = 0; i < 8; ++i) f[i] = s4[i];

#pragma unroll
    for (int gi = 0; gi < 4; ++gi) {
        float4 lo = f[2 * gi], hi4 = f[2 * gi + 1];
        u16x8 o;
        if (DO_DEQUANT) {
            o[0] = f2bf(dequant(lo.x));  o[1] = f2bf(dequant(lo.y));
            o[2] = f2bf(dequant(lo.z));  o[3] = f2bf(dequant(lo.w));
            o[4] = f2bf(dequant(hi4.x)); o[5] = f2bf(dequant(hi4.y));
            o[6] = f2bf(dequant(hi4.z)); o[7] = f2bf(dequant(hi4.w));
        } else {
            o[0] = f2bf(lo.x);  o[1] = f2bf(lo.y);  o[2] = f2bf(lo.z);  o[3] = f2bf(lo.w);
            o[4] = f2bf(hi4.x); o[5] = f2bf(hi4.y); o[6] = f2bf(hi4.z); o[7] = f2bf(hi4.w);
        }
        const int S_rel = 2 * j + (gi >> 1);
        const int slot  = ((gi & 1) << 5) + r;
        *(u16x8*)(lsm + S_rel * 1024 + slot * 16) = o;
    }
    __syncthreads();

    unsigned short* gdst = dst + (((size_t)b * (K >> 4) + (kc << 4)) << 9) + (size_t)t * 32;
#pragma unroll
    for (int i = 0; i < 4; ++i)
        *(u16x8*)(gdst + i * 8) = *(const u16x8*)(lsm + t * 64 + i * 16);
}

// ---------------------------------------------------------------------------
// 256x128 bf16 GEMM, 32x32x16 MFMA, 2 blocks/CU for cross-block TLP.
// C[M,N] = A[M,K] * B[N,K]^T + bias, fp32 out.
// 8 waves (4Mx2N grid), per-wave 64x64 = 2x2 frags (acc 64 AGPR).
// BK=32 tiles, LDS = 2 bufs x 24 KB (A 16KB + B 8KB) = 48 KB.
// Per-tile schedule (frag double-buffer in regs):
//   lgkmcnt(0); BAR1   -> all waves' reads(i) done, buf X free
//   stage X <- tile i+2 (3x 1KB global_load_lds per wave)
//   vmcnt(3); BAR2     -> tile i+1 (buf Y) staged & visible
//   ds_read frags(i+1) from Y; MFMA(i) on current frags (overlap)
// Reads lane-linear (base + l*16): zero bank conflicts. Counted vmcnt only.
// launch_bounds(512,4): cap 128 regs/wave -> 2 resident blocks per CU.
// ---------------------------------------------------------------------------

__global__ __launch_bounds__(512, 4) void gemm256x128_kernel(
        const unsigned short* __restrict__ Ap,  // M x K, packed chunk-linear
        const unsigned short* __restrict__ Bp,  // N x K, packed chunk-linear
        const float* __restrict__ bias,         // N
        float* __restrict__ C,                  // M x N
        int M, int N, int K) {
    __shared__ char ldsB[49152];                // 2 x 24 KB

    const int t    = threadIdx.x;
    const int w    = t >> 6;        // wave 0..7
    const int l    = t & 63;
    const int wr   = w >> 1;        // 0..3  (64-row band)
    const int wc   = w & 1;         // 0..1  (64-col band)
    const int lr32 = l & 31;
    const int hi   = l >> 5;
    const int l16  = l << 4;

    // XCD-aware block swizzle (bijective when nwg % 8 == 0)
    const int nwg = gridDim.x;
    int bid = blockIdx.x;
    if ((nwg & 7) == 0) bid = (bid & 7) * (nwg >> 3) + (bid >> 3);
    const int nbn  = N >> 7;
    const int brow = (bid / nbn) << 8;
    const int bcol = (bid % nbn) << 7;

    // packed staging bases: wave w stages A band w (2 chunks) + B band w>>1, S-parity w&1
    const int Kc = K >> 4;          // S-chunks per row-band
    const char* pA = (const char*)Ap + (((size_t)((brow >> 5) + w)        * (size_t)Kc) << 10) + l16;
    const char* pB = (const char*)Bp + (((size_t)((bcol >> 5) + (w >> 1)) * (size_t)Kc) << 10) + l16;
    const int wpar = w & 1;

    // stage tile i2 into buffer at byte offset BO (0 or 24576)
#define STAGE(i2, BO)                                                                     \
    do {                                                                                  \
        const size_t sa_ = (size_t)(i2) << 11;                                            \
        GLD16(pA + sa_,        ldsB + (BO) + (w << 11));                                  \
        GLD16(pA + sa_ + 1024, ldsB + (BO) + (w << 11) + 1024);                           \
        GLD16(pB + ((size_t)(((i2) << 1) + wpar) << 10), ldsB + (BO) + 16384 + (w << 10));\
    } while (0)

    // read this wave's 8 frags from buffer at offset BO
#define READF(BO, Af, Bf)                                                                 \
    do {                                                                                  \
        _Pragma("unroll") for (int mi = 0; mi < 2; ++mi)                                  \
        _Pragma("unroll") for (int ks = 0; ks < 2; ++ks)                                  \
            Af[mi][ks] = *(const bfrag_t*)(ldsB + (BO) +                                  \
                (((((wr << 1) + mi) << 1) | ks) << 10) + l16);                            \
        _Pragma("unroll") for (int nn = 0; nn < 2; ++nn)                                  \
        _Pragma("unroll") for (int ks = 0; ks < 2; ++ks)                                  \
            Bf[nn][ks] = *(const bfrag_t*)(ldsB + (BO) + 16384 +                          \
                (((((wc << 1) + nn) << 1) | ks) << 10) + l16);                            \
    } while (0)

#define MFMA8(Af, Bf)                                                                     \
    do {                                                                                  \
        __builtin_amdgcn_s_setprio(1);                                                    \
        _Pragma("unroll") for (int ks = 0; ks < 2; ++ks)                                  \
        _Pragma("unroll") for (int mi = 0; mi < 2; ++mi)                                  \
        _Pragma("unroll") for (int nn = 0; nn < 2; ++nn)                                  \
            acc[mi][nn] = __builtin_amdgcn_mfma_f32_32x32x16_bf16(                        \
                Af[mi][ks], Bf[nn][ks], acc[mi][nn], 0, 0, 0);                            \
        __builtin_amdgcn_s_setprio(0);                                                    \
    } while (0)

    // body for one K-tile: X = buf holding tile i (free after BAR1), Y = other
#define BODY(i, XO, YO, Aalt, Balt, Acur, Bcur)                                           \
    do {                                                                                  \
        int i2_ = (i) + 2; if (i2_ >= NT) i2_ -= NT;   /* wrapped: staged, never read */  \
        WAITLGKM0();        /* own reads(i) drained */                                    \
        BAR();              /* all waves' reads(i) done -> X free */                      \
        STAGE(i2_, XO);                                                                   \
        WAITVM(3);          /* tile i+1 (3 GLDs issued last iter) complete */             \
        BAR();              /* i+1 visible block-wide */                                  \
        READF(YO, Aalt, Balt);   /* reads(i+1); drain under MFMA + next BAR1 */           \
        MFMA8(Acur, Bcur);                                                                \
    } while (0)

    f32x16 acc[2][2];
#pragma unroll
    for (int m = 0; m < 2; ++m)
#pragma unroll
        for (int n = 0; n < 2; ++n)
#pragma unroll
            for (int r = 0; r < 16; ++r)
                acc[m][n][r] = 0.f;

    const int NT = K >> 5;          // BK=32 tiles (NT even, >= 8)

    bfrag_t aA[2][2], bA[2][2], aB[2][2], bB[2][2];

    // ---- prologue: stage tiles 0 (buf0) and 1 (buf1); read frags(0) ----
    STAGE(0, 0);
    STAGE(1, 24576);
    WAITVM(3);          // tile 0's 3 complete; tile 1's in flight
    BAR();
    READF(0, aA, bA);

    for (int i = 0; i < NT; i += 2) {
        BODY(i,     0,     24576, aB, bB, aA, bA);
        BODY(i + 1, 24576, 0,     aA, bA, aB, bB);
    }

    WAITVM(0);          // drain pending LDS writes before wave retires

    // ---- epilogue: 32x32 C/D layout col=lane&31, row=(reg&3)+8*(reg>>2)+4*(lane>>5) ----
    float bv[2];
#pragma unroll
    for (int nn = 0; nn < 2; ++nn) bv[nn] = bias[bcol + (wc << 6) + nn * 32 + lr32];
#pragma unroll
    for (int mm = 0; mm < 2; ++mm) {
#pragma unroll
        for (int nn = 0; nn < 2; ++nn) {
            const int gc = bcol + (wc << 6) + nn * 32 + lr32;
#pragma unroll
            for (int reg = 0; reg < 16; ++reg) {
                const int row = (reg & 3) + 8 * (reg >> 2) + 4 * hi;
                C[(size_t)(brow + (wr << 6) + mm * 32 + row) * N + gc] = acc[mm][nn][reg] + bv[nn];
            }
        }
    }
    (void)M;
#undef STAGE
#undef READF
#undef MFMA8
#undef BODY
}

// ---------------------------------------------------------------------------
// Fallback: fp32 tiled GEMM with on-the-fly dequant (any shape, slow).
// ---------------------------------------------------------------------------
__global__ void gemm_fallback_kernel(const float* __restrict__ X, const float* __restrict__ W,
                                     const float* __restrict__ bias, float* __restrict__ C,
                                     int M, int N, int K) {
    __shared__ float sX[16][17];
    __shared__ float sW[16][17];
    const int tx = threadIdx.x & 15;
    const int ty = threadIdx.x >> 4;
    const int row = blockIdx.y * 16 + ty;
    const int colBase = blockIdx.x * 16;
    const int col = colBase + tx;
    float acc = 0.f;
    for (int k0 = 0; k0 < K; k0 += 16) {
        sX[ty][tx] = (row < M && k0 + tx < K) ? X[(size_t)row * K + k0 + tx] : 0.f;
        const int wrow = colBase + ty;
        sW[ty][tx] = (wrow < N && k0 + tx < K) ? dequant(W[(size_t)wrow * K + k0 + tx]) : 0.f;
        __syncthreads();
#pragma unroll
        for (int kk = 0; kk < 16; ++kk)
            acc += sX[ty][kk] * sW[tx][kk];
        __syncthreads();
    }
    if (row < M && col < N)
        C[(size_t)row * N + col] = acc + bias[col];
}

extern "C" void kernel_launch(void* const* d_in, const int* in_sizes, int n_in,
                              void* d_out, int out_size, void* d_ws, size_t ws_size,
                              hipStream_t stream) {
    const float* x    = (const float*)d_in[0];
    const float* w    = (const float*)d_in[1];
    const float* bias = (const float*)d_in[2];
    float* out        = (float*)d_out;

    const int N = in_sizes[2];
    const int K = in_sizes[1] / N;
    const int M = in_sizes[0] / K;

    const size_t need = ((size_t)M * K + (size_t)N * K) * sizeof(unsigned short);
    const bool fast = (ws_size >= need) && (M % 256 == 0) && (N % 128 == 0) &&
                      (K % 256 == 0);

    if (fast) {
        unsigned short* xp = (unsigned short*)d_ws;
        unsigned short* wp = xp + (size_t)M * K;
        pack_kernel<false><<<dim3((M / 32) * (K / 256)), dim3(256), 0, stream>>>(x, xp, K);
        pack_kernel<true ><<<dim3((N / 32) * (K / 256)), dim3(256), 0, stream>>>(w, wp, K);
        gemm256x128_kernel<<<dim3((M / 256) * (N / 128)), dim3(512), 0, stream>>>(xp, wp, bias, out, M, N, K);
    } else {
        dim3 g((N + 15) / 16, (M + 15) / 16);
        gemm_fallback_kernel<<<g, dim3(256), 0, stream>>>(x, w, bias, out, M, N, K);
    }
    (void)n_in; (void)out_size;
}

// Round 8
// 271.805 us; speedup vs baseline: 3.0083x; 3.0083x over previous
//
#include <hip/hip_runtime.h>
#include <stdint.h>

#define THRESH 0.5f
#define PSI 0.1f

typedef short bfrag_t __attribute__((ext_vector_type(8)));     // 8 bf16 = 4 VGPRs (MFMA A/B frag)
typedef float f32x4 __attribute__((ext_vector_type(4)));       // 16x16 MFMA C/D frag
typedef unsigned short u16x8 __attribute__((ext_vector_type(8)));

// async global->LDS, 16B per lane, wave-uniform LDS base + lane*16
#define GLD16(gsrc, ldst)                                                                \
    __builtin_amdgcn_global_load_lds((const __attribute__((address_space(1))) void*)(gsrc), \
                                     (__attribute__((address_space(3))) void*)(ldst),       \
                                     16, 0, 0)

#define WAITVM(n) asm volatile("s_waitcnt vmcnt(" #n ")" ::: "memory")
#define WAITLGKM0() asm volatile("s_waitcnt lgkmcnt(0)" ::: "memory")
#define BAR()                                  \
    do {                                       \
        asm volatile("" ::: "memory");         \
        __builtin_amdgcn_s_barrier();          \
        asm volatile("" ::: "memory");         \
    } while (0)

__device__ __forceinline__ float dequant(float v) {
    if (v > THRESH) return 1.0f;
    if (v < -THRESH) return -1.0f;
    if (fabsf(v) < PSI) return 0.0f;
    return (v + THRESH) / (2.0f * THRESH);
}

__device__ __forceinline__ unsigned short f2bf(float f) {
    unsigned int u = __float_as_uint(f);
    u += 0x7FFFu + ((u >> 16) & 1u);
    return (unsigned short)(u >> 16);
}

// ---------------------------------------------------------------------------
// Packing kernels: fp32 row-major [R][K] -> bf16 chunk-linear:
//   granule (r, S, hi) = 8 elems src[r][16S+8hi .. +7]
//   packed elem offset = ((r/32)*(K/16) + S)*512 + (hi*32 + (r&31))*8
// ---------------------------------------------------------------------------
template <bool DO_DEQUANT>
__global__ void pack_kernel(const float* __restrict__ src, unsigned short* __restrict__ dst, int K) {
    __shared__ char lsm[16384];
    const int t   = threadIdx.x;       // 0..255
    const int nkc = K >> 8;            // K/256
    const int b   = blockIdx.x / nkc;  // 32-row band
    const int kc  = blockIdx.x % nkc;
    const int k0  = kc << 8;
    const int r   = t >> 3;            // 0..31 row within band
    const int j   = t & 7;             // 0..7  32-float group

    const float4* s4 = (const float4*)(src + (size_t)((b << 5) + r) * K + k0 + (j << 5));
    float4 f[8];
#pragma unroll
    for (int i = 0; i < 8; ++i) f[i] = s4[i];

#pragma unroll
    for (int gi = 0; gi < 4; ++gi) {
        float4 lo = f[2 * gi], hi4 = f[2 * gi + 1];
        u16x8 o;
        if (DO_DEQUANT) {
            o[0] = f2bf(dequant(lo.x));  o[1] = f2bf(dequant(lo.y));
            o[2] = f2bf(dequant(lo.z));  o[3] = f2bf(dequant(lo.w));
            o[4] = f2bf(dequant(hi4.x)); o[5] = f2bf(dequant(hi4.y));
            o[6] = f2bf(dequant(hi4.z)); o[7] = f2bf(dequant(hi4.w));
        } else {
            o[0] = f2bf(lo.x);  o[1] = f2bf(lo.y);  o[2] = f2bf(lo.z);  o[3] = f2bf(lo.w);
            o[4] = f2bf(hi4.x); o[5] = f2bf(hi4.y); o[6] = f2bf(hi4.z); o[7] = f2bf(hi4.w);
        }
        const int S_rel = 2 * j + (gi >> 1);
        const int slot  = ((gi & 1) << 5) + r;
        *(u16x8*)(lsm + S_rel * 1024 + slot * 16) = o;
    }
    __syncthreads();

    unsigned short* gdst = dst + (((size_t)b * (K >> 4) + (kc << 4)) << 9) + (size_t)t * 32;
#pragma unroll
    for (int i = 0; i < 4; ++i)
        *(u16x8*)(gdst + i * 8) = *(const u16x8*)(lsm + t * 64 + i * 16);
}

// ---------------------------------------------------------------------------
// 256x256 bf16 GEMM, 16x16x32 MFMA, m201-style quadrant phase schedule.
// C[M,N] = A[M,K] * B[N,K]^T + bias, fp32 out.
// 8 waves (2Mx4N), per-wave 128x64; acc[8][4] f32x4 (128 VGPR).
// LDS 128 KiB = 2 bufs x halves {A rows0-127, A rows128-255, B cols0-127,
// B cols128-255}, each 16 KiB = 16 chunk-linear 1KB granuled chunks.
// Per K-tile (BK=64), 4 phases, quadrants of the 128x64 wave tile:
//   P1 (q00): read A-quad0 (8 b128) + B-quad0 (4); stage Y.A0<-t+1; BAR;
//             lgkm0; 16 MFMA (full K=64); BAR
//   P2 (q01): read B-quad1 (4); stage Y.A1<-t+1; ...
//   P3 (q11): read A-quad1 (8); stage X.B0<-t+2; ...
//   P4 (q10): no reads (A1,B0 reused from regs); stage X.B1<-t+2;
//             BAR; 16 MFMA; vmcnt(4); BAR
// One counted vmcnt(4)/tile (2 half-tiles in flight), never 0 in-loop.
// All ds_reads lane-linear within 256B blocks: zero bank conflicts.
// WAR: each staged region's last read is >=1 full phase (lgkm0+BAR) earlier.
// RAW: Y(t+1) halves staged at t-1:P3/P4 + t:P1/P2; vmcnt(4)@t:P4 leaves only
//      t:P3/P4 outstanding -> Y complete; BAR publishes.
// ---------------------------------------------------------------------------

__global__ __launch_bounds__(512, 2) void gemm256q_kernel(
        const unsigned short* __restrict__ Ap,  // M x K, packed chunk-linear
        const unsigned short* __restrict__ Bp,  // N x K, packed chunk-linear
        const float* __restrict__ bias,         // N
        float* __restrict__ C,                  // M x N
        int M, int N, int K) {
    __shared__ char ldsB[131072];   // 2 bufs x {A0:0, A1:16K, B0:32K, B1:48K}

    const int t   = threadIdx.x;
    const int w   = t >> 6;         // wave 0..7
    const int l   = t & 63;
    const int wr  = w >> 2;         // 0..1  (128-row band)
    const int wc  = w & 3;          // 0..3  (64-col band)
    const int lr  = l & 15;
    const int kg  = l >> 4;
    const int l16 = l << 4;
    // lane offset within a (chunk-pair, slot) frag read; 16-lane groups each
    // cover a distinct 256B-aligned block -> conflict-free
    const int LOFS = ((l >> 5) << 10) + (((l >> 4) & 1) << 9) + (lr << 4);

    // XCD-aware block swizzle (bijective when nwg % 8 == 0)
    const int nwg = gridDim.x;
    int bid = blockIdx.x;
    if ((nwg & 7) == 0) bid = (bid & 7) * (nwg >> 3) + (bid >> 3);
    const int nbn  = N >> 8;
    const int brow = (bid / nbn) << 8;
    const int bcol = (bid % nbn) << 8;

    // packed staging bases: per half-tile, wave w stages 2 consecutive chunks
    // (band w>>1 within the half, S-pair (w&1)*2) -> contiguous 2KB bursts
    const int Kc  = K >> 4;
    const int Sr0 = (w & 1) << 1;
    const char* pA0 = (const char*)Ap + ((((size_t)((brow >> 5) + (w >> 1))) * Kc + Sr0) << 10) + l16;
    const char* pA1 = pA0 + ((size_t)Kc << 12);   // +4 row-bands
    const char* pB0 = (const char*)Bp + ((((size_t)((bcol >> 5) + (w >> 1))) * Kc + Sr0) << 10) + l16;
    const char* pB1 = pB0 + ((size_t)Kc << 12);

#define STAGE(bufO, halfO, p, tv)                                                         \
    do {                                                                                  \
        GLD16((p) + ((size_t)(tv) << 12),        ldsB + (bufO) + (halfO) + (w << 11));    \
        GLD16((p) + ((size_t)(tv) << 12) + 1024, ldsB + (bufO) + (halfO) + (w << 11) + 1024); \
    } while (0)

    // A frag (quad qm, frag-row fm 0..3, kk 0..1) from A-half(wr) of buf XO
#define RD_A(XO, qm, fm, kk)                                                              \
    (*(const bfrag_t*)(ldsB + (XO) + (wr << 14) + ((qm) << 13) + (((fm) >> 1) << 12) +    \
                       ((kk) << 11) + (((fm) & 1) << 8) + LOFS))
    // B frag (quad qn, frag-col fn 0..1, kk) from B-half(wc>>1)
#define RD_B(XO, qn, fn, kk)                                                              \
    (*(const bfrag_t*)(ldsB + (XO) + 32768 + ((wc >> 1) << 14) + ((wc & 1) << 13) +       \
                       ((qn) << 12) + ((kk) << 11) + ((fn) << 8) + LOFS))

#define MFMAQ(qm, qn, bq)                                                                 \
    do {                                                                                  \
        __builtin_amdgcn_s_setprio(1);                                                    \
        _Pragma("unroll") for (int kk = 0; kk < 2; ++kk)                                  \
        _Pragma("unroll") for (int fm = 0; fm < 4; ++fm)                                  \
        _Pragma("unroll") for (int fn = 0; fn < 2; ++fn)                                  \
            acc[(qm) * 4 + fm][(qn) * 2 + fn] = __builtin_amdgcn_mfma_f32_16x16x32_bf16(  \
                a[fm][kk], bq[fn][kk], acc[(qm) * 4 + fm][(qn) * 2 + fn], 0, 0, 0);       \
        __builtin_amdgcn_s_setprio(0);                                                    \
    } while (0)

    f32x4 acc[8][4];
#pragma unroll
    for (int m = 0; m < 8; ++m)
#pragma unroll
        for (int n = 0; n < 4; ++n)
            acc[m][n] = f32x4{0.f, 0.f, 0.f, 0.f};

    const int NT = K >> 6;          // BK=64 tiles; NT even, >= 4

    // ---- prologue: buf0 <- tile0 (B0,B1,A0,A1), buf1 <- tile1 (B0,B1) ----
    STAGE(0, 32768, pB0, 0); STAGE(0, 49152, pB1, 0);
    STAGE(0, 0,     pA0, 0); STAGE(0, 16384, pA1, 0);
    STAGE(65536, 32768, pB0, 1); STAGE(65536, 49152, pB1, 1);
    WAITVM(4);      // buf0 complete; buf1.B* (4 issues) stay in flight
    BAR();

    bfrag_t a[4][2], b0f[2][2], b1f[2][2];

#define TILE(tv, XO, YO)                                                                  \
    do {                                                                                  \
        int t1_ = (tv) + 1; if (t1_ >= NT) t1_ -= NT;  /* wrapped: harmless */            \
        int t2_ = (tv) + 2; if (t2_ >= NT) t2_ -= NT;                                     \
        /* P1: quad(0,0) */                                                               \
        _Pragma("unroll") for (int fm = 0; fm < 4; ++fm)                                  \
        _Pragma("unroll") for (int kk = 0; kk < 2; ++kk) a[fm][kk] = RD_A(XO, 0, fm, kk); \
        _Pragma("unroll") for (int fn = 0; fn < 2; ++fn)                                  \
        _Pragma("unroll") for (int kk = 0; kk < 2; ++kk) b0f[fn][kk] = RD_B(XO, 0, fn, kk); \
        STAGE(YO, 0, pA0, t1_);                                                           \
        BAR(); WAITLGKM0();                                                               \
        MFMAQ(0, 0, b0f);                                                                 \
        BAR();                                                                            \
        /* P2: quad(0,1) */                                                               \
        _Pragma("unroll") for (int fn = 0; fn < 2; ++fn)                                  \
        _Pragma("unroll") for (int kk = 0; kk < 2; ++kk) b1f[fn][kk] = RD_B(XO, 1, fn, kk); \
        STAGE(YO, 16384, pA1, t1_);                                                       \
        BAR(); WAITLGKM0();                                                               \
        MFMAQ(0, 1, b1f);                                                                 \
        BAR();                                                                            \
        /* P3: quad(1,1) */                                                               \
        _Pragma("unroll") for (int fm = 0; fm < 4; ++fm)                                  \
        _Pragma("unroll") for (int kk = 0; kk < 2; ++kk) a[fm][kk] = RD_A(XO, 1, fm, kk); \
        STAGE(XO, 32768, pB0, t2_);                                                       \
        BAR(); WAITLGKM0();                                                               \
        MFMAQ(1, 1, b1f);                                                                 \
        BAR();                                                                            \
        /* P4: quad(1,0) — no reads, A1/B0 reused from regs */                            \
        STAGE(XO, 49152, pB1, t2_);                                                       \
        BAR();                                                                            \
        MFMAQ(1, 0, b0f);                                                                 \
        WAITVM(4);   /* leaves only this tile's P3/P4 stages outstanding */               \
        BAR();                                                                            \
    } while (0)

    for (int tt = 0; tt < NT; tt += 2) {
        TILE(tt, 0, 65536);
        TILE(tt + 1, 65536, 0);
    }

    WAITVM(0);      // drain pending LDS writes before wave retires

    // ---- epilogue: 16x16 C/D layout col=lane&15, row=(lane>>4)*4+reg ----
    float bv[4];
#pragma unroll
    for (int nn = 0; nn < 4; ++nn) bv[nn] = bias[bcol + (wc << 6) + nn * 16 + lr];
#pragma unroll
    for (int mi = 0; mi < 8; ++mi) {
        const int gr = brow + (wr << 7) + mi * 16 + (kg << 2);
#pragma unroll
        for (int nn = 0; nn < 4; ++nn) {
            const int gc = bcol + (wc << 6) + nn * 16 + lr;
#pragma unroll
            for (int j = 0; j < 4; ++j)
                C[(size_t)(gr + j) * N + gc] = acc[mi][nn][j] + bv[nn];
        }
    }
    (void)M;
#undef STAGE
#undef RD_A
#undef RD_B
#undef MFMAQ
#undef TILE
}

// ---------------------------------------------------------------------------
// Fallback: fp32 tiled GEMM with on-the-fly dequant (any shape, slow).
// ---------------------------------------------------------------------------
__global__ void gemm_fallback_kernel(const float* __restrict__ X, const float* __restrict__ W,
                                     const float* __restrict__ bias, float* __restrict__ C,
                                     int M, int N, int K) {
    __shared__ float sX[16][17];
    __shared__ float sW[16][17];
    const int tx = threadIdx.x & 15;
    const int ty = threadIdx.x >> 4;
    const int row = blockIdx.y * 16 + ty;
    const int colBase = blockIdx.x * 16;
    const int col = colBase + tx;
    float acc = 0.f;
    for (int k0 = 0; k0 < K; k0 += 16) {
        sX[ty][tx] = (row < M && k0 + tx < K) ? X[(size_t)row * K + k0 + tx] : 0.f;
        const int wrow = colBase + ty;
        sW[ty][tx] = (wrow < N && k0 + tx < K) ? dequant(W[(size_t)wrow * K + k0 + tx]) : 0.f;
        __syncthreads();
#pragma unroll
        for (int kk = 0; kk < 16; ++kk)
            acc += sX[ty][kk] * sW[tx][kk];
        __syncthreads();
    }
    if (row < M && col < N)
        C[(size_t)row * N + col] = acc + bias[col];
}

extern "C" void kernel_launch(void* const* d_in, const int* in_sizes, int n_in,
                              void* d_out, int out_size, void* d_ws, size_t ws_size,
                              hipStream_t stream) {
    const float* x    = (const float*)d_in[0];
    const float* w    = (const float*)d_in[1];
    const float* bias = (const float*)d_in[2];
    float* out        = (float*)d_out;

    const int N = in_sizes[2];
    const int K = in_sizes[1] / N;
    const int M = in_sizes[0] / K;

    const size_t need = ((size_t)M * K + (size_t)N * K) * sizeof(unsigned short);
    const bool fast = (ws_size >= need) && (M % 256 == 0) && (N % 256 == 0) &&
                      (K % 256 == 0);

    if (fast) {
        unsigned short* xp = (unsigned short*)d_ws;
        unsigned short* wp = xp + (size_t)M * K;
        pack_kernel<false><<<dim3((M / 32) * (K / 256)), dim3(256), 0, stream>>>(x, xp, K);
        pack_kernel<true ><<<dim3((N / 32) * (K / 256)), dim3(256), 0, stream>>>(w, wp, K);
        gemm256q_kernel<<<dim3((M / 256) * (N / 256)), dim3(512), 0, stream>>>(xp, wp, bias, out, M, N, K);
    } else {
        dim3 g((N + 15) / 16, (M + 15) / 16);
        gemm_fallback_kernel<<<g, dim3(256), 0, stream>>>(x, w, bias, out, M, N, K);
    }
    (void)n_in; (void)out_size;
}